// Round 1
// baseline (23270.465 us; speedup 1.0000x reference)
//
#include <hip/hip_runtime.h>

#define ALPHA 0.9f
#define THRESH 1.0f
#define BATCH 512
#define CIN 16
#define TSTEPS 2000
#define NRES 1024
#define NCLS 10

// ---------------------------------------------------------------------------
// Transpose W_res (1024x1024) -> Wt so that Wt[j][n] = W_res[n][j].
// Then (s @ W_res^T)[n] = sum over active j of Wt[j][n]  (contiguous rows).
// ---------------------------------------------------------------------------
__global__ __launch_bounds__(256) void wres_transpose(const float* __restrict__ W,
                                                      float* __restrict__ Wt) {
    __shared__ float tile[32][33];
    const int bx = blockIdx.x * 32, by = blockIdx.y * 32;
    const int tx = threadIdx.x & 31;
    const int ty = threadIdx.x >> 5;  // 0..7
#pragma unroll
    for (int r = ty; r < 32; r += 8) tile[r][tx] = W[(by + r) * NRES + bx + tx];
    __syncthreads();
#pragma unroll
    for (int r = ty; r < 32; r += 8) Wt[(bx + r) * NRES + by + tx] = tile[tx][r];
}

// ---------------------------------------------------------------------------
// One block per batch row; runs all TSTEPS locally. Thread tid owns neurons
// n = 4*tid .. 4*tid+3 (v, spike-count accumulator in registers).
// Spikes stored as a 1024-bit LDS mask (double-buffered) and expanded each
// step into an ascending-j index list (deterministic order) for the sparse
// recurrent accumulation.
// ---------------------------------------------------------------------------
__global__ __launch_bounds__(256) void reservoir_kernel(
    const float* __restrict__ x,       // (B, C, T)
    const float* __restrict__ W_in,    // (NRES, CIN)
    const float* __restrict__ W_clf,   // (NCLS, NRES)
    const float4* __restrict__ Wt4,    // (NRES, NRES) transposed, as float4
    float* __restrict__ out)           // [B*NCLS] ++ [B*NRES]
{
    const int b = blockIdx.x;
    const int tid = (int)threadIdx.x;
    const int lane = tid & 63;
    const int wv = tid >> 6;

    __shared__ float xs[CIN];
    __shared__ unsigned mask[2][32];   // 1024 bits each, double-buffered
    __shared__ int list[NRES];
    __shared__ int cntS;
    __shared__ float red[4][NCLS];
    __shared__ float vc[NCLS], accc[NCLS];

    if (tid < 32) { mask[0][tid] = 0u; mask[1][tid] = 0u; }
    if (tid < NCLS) { vc[tid] = 0.f; accc[tid] = 0.f; }

    const int n0 = tid * 4;
    // W_in rows for my 4 neurons, transposed into registers: win[c] = {W_in[n0+i][c]}
    float4 win[CIN];
#pragma unroll
    for (int c = 0; c < CIN; ++c) {
        win[c].x = W_in[(n0 + 0) * CIN + c];
        win[c].y = W_in[(n0 + 1) * CIN + c];
        win[c].z = W_in[(n0 + 2) * CIN + c];
        win[c].w = W_in[(n0 + 3) * CIN + c];
    }
    float4 wclf[NCLS];
#pragma unroll
    for (int k = 0; k < NCLS; ++k)
        wclf[k] = *(const float4*)(W_clf + k * NRES + n0);

    float4 v   = {0.f, 0.f, 0.f, 0.f};
    float4 acc = {0.f, 0.f, 0.f, 0.f};
    const float* xrow = x + (long)b * CIN * TSTEPS;

    __syncthreads();

    for (int t = 0; t < TSTEPS; ++t) {
        const int cur = t & 1;       // mask[cur] holds spikes from step t-1
        const int nxt = cur ^ 1;

        // ---- stage 1: build index list (wave0 lanes 0..31), zero next mask,
        // ----          stage x_t. Deterministic ascending-j list order.
        if (tid < 32) {
            unsigned m = mask[cur][tid];
            int p = __popc(m);
#pragma unroll
            for (int off = 1; off < 32; off <<= 1) {
                int y = __shfl_up(p, off, 64);
                if (tid >= off) p += y;
            }
            int base = p - __popc(m);
            while (m) {
                int bit = __ffs(m) - 1;
                m &= m - 1u;
                list[base++] = tid * 32 + bit;
            }
            if (tid == 31) cntS = p;
        } else if (tid < 64) {
            mask[nxt][tid - 32] = 0u;
        } else if (tid < 64 + CIN) {
            xs[tid - 64] = xrow[(tid - 64) * TSTEPS + t];
        }
        __syncthreads();

        // ---- input projection: v = alpha*v + x_t . W_in^T
        float4 inp = {0.f, 0.f, 0.f, 0.f};
#pragma unroll
        for (int c = 0; c < CIN; ++c) {
            const float xc = xs[c];
            inp.x += xc * win[c].x;
            inp.y += xc * win[c].y;
            inp.z += xc * win[c].z;
            inp.w += xc * win[c].w;
        }
        v.x = ALPHA * v.x + inp.x;
        v.y = ALPHA * v.y + inp.y;
        v.z = ALPHA * v.z + inp.z;
        v.w = ALPHA * v.w + inp.w;

        // ---- sparse recurrent accumulation: v += sum_j_active Wt[j][n0..n0+3]
        const int cnt = cntS;
        float4 r0 = {0.f,0.f,0.f,0.f}, r1 = {0.f,0.f,0.f,0.f};
        float4 r2 = {0.f,0.f,0.f,0.f}, r3 = {0.f,0.f,0.f,0.f};
        int i = 0;
        for (; i + 4 <= cnt; i += 4) {
            const int j0 = list[i], j1 = list[i + 1], j2 = list[i + 2], j3 = list[i + 3];
            const float4 a0 = Wt4[j0 * 256 + tid];
            const float4 a1 = Wt4[j1 * 256 + tid];
            const float4 a2 = Wt4[j2 * 256 + tid];
            const float4 a3 = Wt4[j3 * 256 + tid];
            r0.x += a0.x; r0.y += a0.y; r0.z += a0.z; r0.w += a0.w;
            r1.x += a1.x; r1.y += a1.y; r1.z += a1.z; r1.w += a1.w;
            r2.x += a2.x; r2.y += a2.y; r2.z += a2.z; r2.w += a2.w;
            r3.x += a3.x; r3.y += a3.y; r3.z += a3.z; r3.w += a3.w;
        }
        for (; i < cnt; ++i) {
            const float4 a0 = Wt4[list[i] * 256 + tid];
            r0.x += a0.x; r0.y += a0.y; r0.z += a0.z; r0.w += a0.w;
        }
        v.x += (r0.x + r1.x) + (r2.x + r3.x);
        v.y += (r0.y + r1.y) + (r2.y + r3.y);
        v.z += (r0.z + r1.z) + (r2.z + r3.z);
        v.w += (r0.w + r1.w) + (r2.w + r3.w);

        // ---- threshold, reset, accumulate reservoir spike counts
        float4 s;
        s.x = (v.x >= THRESH) ? 1.f : 0.f; if (s.x != 0.f) v.x = 0.f;
        s.y = (v.y >= THRESH) ? 1.f : 0.f; if (s.y != 0.f) v.y = 0.f;
        s.z = (v.z >= THRESH) ? 1.f : 0.f; if (s.z != 0.f) v.z = 0.f;
        s.w = (v.w >= THRESH) ? 1.f : 0.f; if (s.w != 0.f) v.w = 0.f;
        acc.x += s.x; acc.y += s.y; acc.z += s.z; acc.w += s.w;

        // ---- publish spikes into next mask (bit j = 4*tid + i)
        unsigned bits = (s.x != 0.f ? 1u : 0u) | (s.y != 0.f ? 2u : 0u) |
                        (s.z != 0.f ? 4u : 0u) | (s.w != 0.f ? 8u : 0u);
        if (bits) atomicOr(&mask[nxt][tid >> 3], bits << ((tid & 7) * 4));

        // ---- classifier LIF readout: v_c = alpha*v_c + s . W_clf^T
        float p[NCLS];
#pragma unroll
        for (int k = 0; k < NCLS; ++k)
            p[k] = s.x * wclf[k].x + s.y * wclf[k].y + s.z * wclf[k].z + s.w * wclf[k].w;
#pragma unroll
        for (int off = 32; off >= 1; off >>= 1) {
#pragma unroll
            for (int k = 0; k < NCLS; ++k) p[k] += __shfl_xor(p[k], off, 64);
        }
        if (lane == 0) {
#pragma unroll
            for (int k = 0; k < NCLS; ++k) red[wv][k] = p[k];
        }
        __syncthreads();   // also fences mask[nxt] atomics & list/xs reuse

        if (tid < NCLS) {
            const float sum = (red[0][tid] + red[1][tid]) + (red[2][tid] + red[3][tid]);
            float vck = ALPHA * vc[tid] + sum;
            const float sck = (vck >= THRESH) ? 1.f : 0.f;
            accc[tid] += sck;
            vc[tid] = (sck != 0.f) ? 0.f : vck;
        }
    }

    // ---- outputs: spike_counts (B,NCLS) then res_accum (B,NRES)
    if (tid < NCLS) out[b * NCLS + tid] = accc[tid];
    float4* outr = (float4*)(out + BATCH * NCLS + (long)b * NRES);
    outr[tid] = acc;
}

extern "C" void kernel_launch(void* const* d_in, const int* in_sizes, int n_in,
                              void* d_out, int out_size, void* d_ws, size_t ws_size,
                              hipStream_t stream) {
    (void)in_sizes; (void)n_in; (void)out_size; (void)ws_size;
    const float* x     = (const float*)d_in[0];
    const float* W_in  = (const float*)d_in[1];
    const float* W_res = (const float*)d_in[2];
    const float* W_clf = (const float*)d_in[3];
    float* out = (float*)d_out;
    float* Wt  = (float*)d_ws;  // 4 MB scratch for transposed W_res

    dim3 tgrid(32, 32);
    wres_transpose<<<tgrid, 256, 0, stream>>>(W_res, Wt);
    reservoir_kernel<<<BATCH, 256, 0, stream>>>(x, W_in, W_clf, (const float4*)Wt, out);
}

// Round 2
// 22784.126 us; speedup vs baseline: 1.0213x; 1.0213x over previous
//
#include <hip/hip_runtime.h>

#define ALPHA 0.9f
#define THRESH 1.0f
#define BATCH 512
#define CIN 16
#define TSTEPS 2000
#define NRES 1024
#define NCLS 10

// ---------------------------------------------------------------------------
// Transpose + bf16-convert W_res (1024x1024 fp32) -> Wt16 so that
// Wt16[j][n] = bf16(W_res[n][j]). Row j is then 1024*2B = 2KB contiguous,
// and (s @ W_res^T)[n] = sum over active j of Wt16[j][n].
// ---------------------------------------------------------------------------
__device__ __forceinline__ unsigned short bf16_rne(float f) {
    unsigned u = __float_as_uint(f);
    unsigned r = (u + 0x7fffu + ((u >> 16) & 1u)) >> 16;  // round-nearest-even
    return (unsigned short)r;
}

__global__ __launch_bounds__(256) void wres_transpose_bf16(const float* __restrict__ W,
                                                           unsigned short* __restrict__ Wt) {
    __shared__ float tile[64][65];
    const int j0 = blockIdx.x * 64, n0 = blockIdx.y * 64;
    for (int idx = threadIdx.x; idx < 64 * 64; idx += 256) {
        const int r = idx >> 6, c = idx & 63;
        tile[r][c] = W[(n0 + r) * NRES + j0 + c];  // W[n][j]
    }
    __syncthreads();
    for (int idx = threadIdx.x; idx < 64 * 32; idx += 256) {
        const int jj = idx >> 5;
        const int nn = (idx & 31) * 2;
        ushort2 u;
        u.x = bf16_rne(tile[nn][jj]);
        u.y = bf16_rne(tile[nn + 1][jj]);
        *(ushort2*)&Wt[(j0 + jj) * NRES + n0 + nn] = u;
    }
}

// ---------------------------------------------------------------------------
// One block per batch row; runs all TSTEPS locally. Thread tid owns neurons
// n = 4*tid .. 4*tid+3. Spikes stored as a 1024-bit LDS mask (double-
// buffered), expanded each step into an ascending-j list (deterministic
// order) for the sparse recurrent accumulation over bf16 weight rows.
// ---------------------------------------------------------------------------
__device__ __forceinline__ void add_bf16x4(float4& r, uint2 a) {
    r.x += __uint_as_float(a.x << 16);
    r.y += __uint_as_float(a.x & 0xffff0000u);
    r.z += __uint_as_float(a.y << 16);
    r.w += __uint_as_float(a.y & 0xffff0000u);
}

__global__ __launch_bounds__(256) void reservoir_kernel(
    const float* __restrict__ x,        // (B, C, T)
    const float* __restrict__ W_in,     // (NRES, CIN)
    const float* __restrict__ W_clf,    // (NCLS, NRES)
    const uint2* __restrict__ Wt2,      // (NRES, NRES) transposed bf16; uint2 = 4 weights
    float* __restrict__ out)            // [B*NCLS] ++ [B*NRES]
{
    const int b = blockIdx.x;
    const int tid = (int)threadIdx.x;
    const int lane = tid & 63;
    const int wv = tid >> 6;

    __shared__ float xs[CIN];
    __shared__ unsigned mask[2][32];    // 1024 bits each, double-buffered
    __shared__ int list[NRES];
    __shared__ int cntS;
    __shared__ float red[4][NCLS];
    __shared__ float vc[NCLS], accc[NCLS];

    if (tid < 32) { mask[0][tid] = 0u; mask[1][tid] = 0u; }
    if (tid < NCLS) { vc[tid] = 0.f; accc[tid] = 0.f; }

    const int n0 = tid * 4;
    float4 win[CIN];
#pragma unroll
    for (int c = 0; c < CIN; ++c) {
        win[c].x = W_in[(n0 + 0) * CIN + c];
        win[c].y = W_in[(n0 + 1) * CIN + c];
        win[c].z = W_in[(n0 + 2) * CIN + c];
        win[c].w = W_in[(n0 + 3) * CIN + c];
    }
    float4 wclf[NCLS];
#pragma unroll
    for (int k = 0; k < NCLS; ++k)
        wclf[k] = *(const float4*)(W_clf + k * NRES + n0);

    float4 v   = {0.f, 0.f, 0.f, 0.f};
    float4 acc = {0.f, 0.f, 0.f, 0.f};
    const float* xrow = x + (long)b * CIN * TSTEPS;

    __syncthreads();

    for (int t = 0; t < TSTEPS; ++t) {
        const int cur = t & 1;
        const int nxt = cur ^ 1;

        // ---- stage 1: build ascending-j index list (lanes 0..31 of wave 0),
        // ----          zero next mask, stage x_t.
        if (tid < 32) {
            unsigned m = mask[cur][tid];
            int p = __popc(m);
#pragma unroll
            for (int off = 1; off < 32; off <<= 1) {
                int y = __shfl_up(p, off, 64);
                if (tid >= off) p += y;
            }
            int base = p - __popc(m);
            while (m) {
                int bit = __ffs(m) - 1;
                m &= m - 1u;
                list[base++] = tid * 32 + bit;
            }
            if (tid == 31) cntS = p;
        } else if (tid < 64) {
            mask[nxt][tid - 32] = 0u;
        } else if (tid < 64 + CIN) {
            xs[tid - 64] = xrow[(tid - 64) * TSTEPS + t];
        }
        __syncthreads();

        // ---- input projection: v = alpha*v + x_t . W_in^T
        float4 inp = {0.f, 0.f, 0.f, 0.f};
#pragma unroll
        for (int c = 0; c < CIN; ++c) {
            const float xc = xs[c];
            inp.x += xc * win[c].x;
            inp.y += xc * win[c].y;
            inp.z += xc * win[c].z;
            inp.w += xc * win[c].w;
        }
        v.x = ALPHA * v.x + inp.x;
        v.y = ALPHA * v.y + inp.y;
        v.z = ALPHA * v.z + inp.z;
        v.w = ALPHA * v.w + inp.w;

        // ---- sparse recurrent accumulation: v += sum_j_active Wt16[j][n0..n0+3]
        const int cnt = cntS;
        float4 r0 = {0.f,0.f,0.f,0.f}, r1 = {0.f,0.f,0.f,0.f};
        float4 r2 = {0.f,0.f,0.f,0.f}, r3 = {0.f,0.f,0.f,0.f};
        int i = 0;
        for (; i + 8 <= cnt; i += 8) {
            const uint2 a0 = Wt2[list[i    ] * 256 + tid];
            const uint2 a1 = Wt2[list[i + 1] * 256 + tid];
            const uint2 a2 = Wt2[list[i + 2] * 256 + tid];
            const uint2 a3 = Wt2[list[i + 3] * 256 + tid];
            const uint2 a4 = Wt2[list[i + 4] * 256 + tid];
            const uint2 a5 = Wt2[list[i + 5] * 256 + tid];
            const uint2 a6 = Wt2[list[i + 6] * 256 + tid];
            const uint2 a7 = Wt2[list[i + 7] * 256 + tid];
            add_bf16x4(r0, a0); add_bf16x4(r1, a1);
            add_bf16x4(r2, a2); add_bf16x4(r3, a3);
            add_bf16x4(r0, a4); add_bf16x4(r1, a5);
            add_bf16x4(r2, a6); add_bf16x4(r3, a7);
        }
        for (; i < cnt; ++i) {
            const uint2 a0 = Wt2[list[i] * 256 + tid];
            add_bf16x4(r0, a0);
        }
        v.x += (r0.x + r1.x) + (r2.x + r3.x);
        v.y += (r0.y + r1.y) + (r2.y + r3.y);
        v.z += (r0.z + r1.z) + (r2.z + r3.z);
        v.w += (r0.w + r1.w) + (r2.w + r3.w);

        // ---- threshold, reset, accumulate reservoir spike counts
        float4 s;
        s.x = (v.x >= THRESH) ? 1.f : 0.f; if (s.x != 0.f) v.x = 0.f;
        s.y = (v.y >= THRESH) ? 1.f : 0.f; if (s.y != 0.f) v.y = 0.f;
        s.z = (v.z >= THRESH) ? 1.f : 0.f; if (s.z != 0.f) v.z = 0.f;
        s.w = (v.w >= THRESH) ? 1.f : 0.f; if (s.w != 0.f) v.w = 0.f;
        acc.x += s.x; acc.y += s.y; acc.z += s.z; acc.w += s.w;

        // ---- publish spikes into next mask (bit j = 4*tid + i)
        unsigned bits = (s.x != 0.f ? 1u : 0u) | (s.y != 0.f ? 2u : 0u) |
                        (s.z != 0.f ? 4u : 0u) | (s.w != 0.f ? 8u : 0u);
        if (bits) atomicOr(&mask[nxt][tid >> 3], bits << ((tid & 7) * 4));

        // ---- classifier LIF readout: v_c = alpha*v_c + s . W_clf^T
        float p[NCLS];
#pragma unroll
        for (int k = 0; k < NCLS; ++k)
            p[k] = s.x * wclf[k].x + s.y * wclf[k].y + s.z * wclf[k].z + s.w * wclf[k].w;
#pragma unroll
        for (int off = 32; off >= 1; off >>= 1) {
#pragma unroll
            for (int k = 0; k < NCLS; ++k) p[k] += __shfl_xor(p[k], off, 64);
        }
        if (lane == 0) {
#pragma unroll
            for (int k = 0; k < NCLS; ++k) red[wv][k] = p[k];
        }
        __syncthreads();   // also fences mask[nxt] atomics & list/xs reuse

        if (tid < NCLS) {
            const float sum = (red[0][tid] + red[1][tid]) + (red[2][tid] + red[3][tid]);
            float vck = ALPHA * vc[tid] + sum;
            const float sck = (vck >= THRESH) ? 1.f : 0.f;
            accc[tid] += sck;
            vc[tid] = (sck != 0.f) ? 0.f : vck;
        }
    }

    // ---- outputs: spike_counts (B,NCLS) then res_accum (B,NRES)
    if (tid < NCLS) out[b * NCLS + tid] = accc[tid];
    float4* outr = (float4*)(out + BATCH * NCLS + (long)b * NRES);
    outr[tid] = acc;
}

extern "C" void kernel_launch(void* const* d_in, const int* in_sizes, int n_in,
                              void* d_out, int out_size, void* d_ws, size_t ws_size,
                              hipStream_t stream) {
    (void)in_sizes; (void)n_in; (void)out_size; (void)ws_size;
    const float* x     = (const float*)d_in[0];
    const float* W_in  = (const float*)d_in[1];
    const float* W_res = (const float*)d_in[2];
    const float* W_clf = (const float*)d_in[3];
    float* out = (float*)d_out;
    unsigned short* Wt = (unsigned short*)d_ws;  // 2 MB scratch: bf16 transposed W_res

    dim3 tgrid(16, 16);
    wres_transpose_bf16<<<tgrid, 256, 0, stream>>>(W_res, Wt);
    reservoir_kernel<<<BATCH, 256, 0, stream>>>(x, W_in, W_clf, (const uint2*)Wt, out);
}

// Round 3
// 20002.791 us; speedup vs baseline: 1.1634x; 1.1390x over previous
//
#include <hip/hip_runtime.h>

#define ALPHA 0.9f
#define THRESH 1.0f
#define BATCH 512
#define CIN 16
#define TSTEPS 2000
#define NRES 1024
#define NCLS 10

typedef float v2f __attribute__((ext_vector_type(2)));

// ---------------------------------------------------------------------------
// Transpose + bf16-convert W_res (1024x1024 fp32) -> Wt16[j][n] = bf16(W[n][j]).
// Row j = 2048 contiguous bytes; (s @ W_res^T)[n] = sum_{active j} Wt16[j][n].
// ---------------------------------------------------------------------------
__device__ __forceinline__ unsigned short bf16_rne(float f) {
    unsigned u = __float_as_uint(f);
    return (unsigned short)((u + 0x7fffu + ((u >> 16) & 1u)) >> 16);
}

__global__ __launch_bounds__(256) void wres_transpose_bf16(const float* __restrict__ W,
                                                           unsigned short* __restrict__ Wt) {
    __shared__ float tile[64][65];
    const int j0 = blockIdx.x * 64, n0 = blockIdx.y * 64;
    for (int idx = threadIdx.x; idx < 64 * 64; idx += 256) {
        const int r = idx >> 6, c = idx & 63;
        tile[r][c] = W[(n0 + r) * NRES + j0 + c];  // W[n][j]
    }
    __syncthreads();
    for (int idx = threadIdx.x; idx < 64 * 32; idx += 256) {
        const int jj = idx >> 5;
        const int nn = (idx & 31) * 2;
        ushort2 u;
        u.x = bf16_rne(tile[nn][jj]);
        u.y = bf16_rne(tile[nn + 1][jj]);
        *(ushort2*)&Wt[(j0 + jj) * NRES + n0 + nn] = u;
    }
}

// bf16 pair -> float2. Low neuron: exact (u<<16). High neuron: raw dword —
// 16 garbage mantissa bits = <=2^-9 relative, below bf16 quantization noise.
__device__ __forceinline__ v2f unp(unsigned u) {
    v2f w;
    w.x = __uint_as_float(u << 16);
    w.y = __uint_as_float(u);
    return w;
}

// ---------------------------------------------------------------------------
// One block (512 threads, 8 waves) per batch row; all TSTEPS run locally.
// Thread owns neurons 2*tid, 2*tid+1. Spikes -> per-wave ballots -> 32 LDS
// mask words (double-buffered); wave 0 compacts them into a byte-offset list;
// wave 1 runs the deferred classifier update; wave 2 prefetches x_{t+1}.
// ---------------------------------------------------------------------------
__global__ __launch_bounds__(512, 4) void reservoir_kernel(
    const float* __restrict__ x,          // (B, C, T)
    const float* __restrict__ W_in,       // (NRES, CIN)
    const float* __restrict__ W_clf,      // (NCLS, NRES)
    const unsigned char* __restrict__ Wt, // bf16 (NRES rows x 2048 B)
    float* __restrict__ out)              // [B*NCLS] ++ [B*NRES]
{
    const int b = blockIdx.x;
    const int tid = (int)threadIdx.x;
    const int lane = tid & 63;
    const int wv = tid >> 6;                 // 0..7

    __shared__ float xs[2][CIN];             // double-buffered x_t
    __shared__ unsigned mw[2][32];           // 1024-bit spike masks
    __shared__ __align__(16) int list[NRES]; // active-row byte offsets
    __shared__ int cntS;
    __shared__ float red[2][8][NCLS];        // per-wave classifier partials
    __shared__ float vcS[NCLS], accS[NCLS];

    // ---- init
    if (tid < 32) mw[0][tid] = 0u;
    if (tid < 2 * 8 * NCLS) ((float*)red)[tid] = 0.f;
    if (tid < NCLS) { vcS[tid] = 0.f; accS[tid] = 0.f; }
    const float* xrow = x + (long)b * CIN * TSTEPS;
    if (tid < CIN) xs[0][tid] = xrow[tid * TSTEPS];

    const int n0 = 2 * tid;
    v2f win[CIN];
#pragma unroll
    for (int c = 0; c < CIN; ++c) {
        win[c].x = W_in[n0 * CIN + c];
        win[c].y = W_in[(n0 + 1) * CIN + c];
    }
    v2f wc[NCLS];
#pragma unroll
    for (int k = 0; k < NCLS; ++k) {
        wc[k].x = W_clf[k * NRES + n0];
        wc[k].y = W_clf[k * NRES + n0 + 1];
    }

    v2f vv  = {0.f, 0.f};
    v2f acc = {0.f, 0.f};

    __syncthreads();

    for (int t = 0; t < TSTEPS; ++t) {
        const int cur = t & 1;
        const int nxt = cur ^ 1;

        // ================= P1: wave-specialized prep =================
        if (wv == 0) {
            if (lane < 32) {
                unsigned m = mw[cur][lane];
                int pc = __popc(m);
#pragma unroll
                for (int off = 1; off < 32; off <<= 1) {
                    int y = __shfl_up(pc, off, 64);
                    if (lane >= off) pc += y;
                }
                int base = pc - __popc(m);
                // word 'lane' = 4*wv' + q: neurons j = jb + 2*bit
                const int jb = 128 * (lane >> 2) + ((lane & 1) << 6) + ((lane >> 1) & 1);
                while (m) {
                    int bit = __ffs((int)m) - 1;
                    m &= m - 1u;
                    list[base++] = (jb + 2 * bit) << 11;  // byte offset (2048 B rows)
                }
                if (lane == 31) cntS = pc;
            }
        } else if (wv == 1) {
            // classifier LIF update for step t-1 (red[nxt]; zeros at t=0)
            if (lane < NCLS) {
                const float sum =
                    ((red[nxt][0][lane] + red[nxt][1][lane]) + (red[nxt][2][lane] + red[nxt][3][lane])) +
                    ((red[nxt][4][lane] + red[nxt][5][lane]) + (red[nxt][6][lane] + red[nxt][7][lane]));
                float vck = ALPHA * vcS[lane] + sum;
                const float sck = (vck >= THRESH) ? 1.f : 0.f;
                accS[lane] += sck;
                vcS[lane] = (sck != 0.f) ? 0.f : vck;
            }
        } else if (wv == 2) {
            if (lane < CIN && t + 1 < TSTEPS)
                xs[nxt][lane] = xrow[lane * TSTEPS + (t + 1)];
        }

        // ---- input projection (all waves): vv = alpha*vv + x_t . W_in^T
        v2f inj = {0.f, 0.f};
        {
            const float* xc = xs[cur];
#pragma unroll
            for (int c = 0; c < CIN; ++c) {
                const float xv = xc[c];
                inj.x += xv * win[c].x;
                inj.y += xv * win[c].y;
            }
        }
        vv = ALPHA * vv + inj;

        __syncthreads();   // B1: list + cnt ready

        // ================= P2: sparse gather =================
        const int cnt = cntS;
        v2f r0 = {0.f,0.f}, r1 = {0.f,0.f}, r2 = {0.f,0.f}, r3 = {0.f,0.f};
        const int vo = tid << 2;  // 4 B per thread within a row
        int i = 0;
        for (; i + 8 <= cnt; i += 8) {
            const int4 oA = *(const int4*)&list[i];
            const int4 oB = *(const int4*)&list[i + 4];
            const unsigned u0 = *(const unsigned*)(Wt + oA.x + vo);
            const unsigned u1 = *(const unsigned*)(Wt + oA.y + vo);
            const unsigned u2 = *(const unsigned*)(Wt + oA.z + vo);
            const unsigned u3 = *(const unsigned*)(Wt + oA.w + vo);
            const unsigned u4 = *(const unsigned*)(Wt + oB.x + vo);
            const unsigned u5 = *(const unsigned*)(Wt + oB.y + vo);
            const unsigned u6 = *(const unsigned*)(Wt + oB.z + vo);
            const unsigned u7 = *(const unsigned*)(Wt + oB.w + vo);
            r0 += unp(u0); r1 += unp(u1); r2 += unp(u2); r3 += unp(u3);
            r0 += unp(u4); r1 += unp(u5); r2 += unp(u6); r3 += unp(u7);
        }
        for (; i < cnt; ++i)
            r0 += unp(*(const unsigned*)(Wt + list[i] + vo));
        vv += (r0 + r1) + (r2 + r3);

        // ---- threshold / reset / count
        const float sx = (vv.x >= THRESH) ? 1.f : 0.f;
        const float sy = (vv.y >= THRESH) ? 1.f : 0.f;
        if (sx != 0.f) vv.x = 0.f;
        if (sy != 0.f) vv.y = 0.f;
        acc.x += sx; acc.y += sy;

        // ---- publish spikes via ballot (no atomics)
        const unsigned long long bx = __ballot(sx != 0.f);
        const unsigned long long by = __ballot(sy != 0.f);
        if (lane == 0) {
            mw[nxt][4 * wv + 0] = (unsigned)bx;
            mw[nxt][4 * wv + 1] = (unsigned)(bx >> 32);
            mw[nxt][4 * wv + 2] = (unsigned)by;
            mw[nxt][4 * wv + 3] = (unsigned)(by >> 32);
        }

        // ---- classifier partials: p[k] = s . W_clf^T (this wave's 128 neurons)
        float p[NCLS];
#pragma unroll
        for (int k = 0; k < NCLS; ++k)
            p[k] = sx * wc[k].x + sy * wc[k].y;
#pragma unroll
        for (int off = 32; off >= 1; off >>= 1) {
#pragma unroll
            for (int k = 0; k < NCLS; ++k) p[k] += __shfl_xor(p[k], off, 64);
        }
        if (lane == 0) {
#pragma unroll
            for (int k = 0; k < NCLS; ++k) red[cur][wv][k] = p[k];
        }

        __syncthreads();   // B2: mw[nxt] + red[cur] visible for next P1
    }

    // ---- epilogue: final classifier step ((TSTEPS-1)&1 == 1) + outputs
    if (wv == 1 && lane < NCLS) {
        const int k = lane;
        const float sum =
            ((red[1][0][k] + red[1][1][k]) + (red[1][2][k] + red[1][3][k])) +
            ((red[1][4][k] + red[1][5][k]) + (red[1][6][k] + red[1][7][k]));
        const float vck = ALPHA * vcS[k] + sum;
        const float sck = (vck >= THRESH) ? 1.f : 0.f;
        out[b * NCLS + k] = accS[k] + sck;
    }
    float2* outr = (float2*)(out + BATCH * NCLS + (long)b * NRES);
    outr[tid] = make_float2(acc.x, acc.y);
}

extern "C" void kernel_launch(void* const* d_in, const int* in_sizes, int n_in,
                              void* d_out, int out_size, void* d_ws, size_t ws_size,
                              hipStream_t stream) {
    (void)in_sizes; (void)n_in; (void)out_size; (void)ws_size;
    const float* x     = (const float*)d_in[0];
    const float* W_in  = (const float*)d_in[1];
    const float* W_res = (const float*)d_in[2];
    const float* W_clf = (const float*)d_in[3];
    float* out = (float*)d_out;
    unsigned short* Wt = (unsigned short*)d_ws;  // 2 MB: bf16 transposed W_res

    dim3 tgrid(16, 16);
    wres_transpose_bf16<<<tgrid, 256, 0, stream>>>(W_res, Wt);
    reservoir_kernel<<<BATCH, 512, 0, stream>>>(x, W_in, W_clf,
                                                (const unsigned char*)Wt, out);
}

// Round 4
// 16121.521 us; speedup vs baseline: 1.4434x; 1.2408x over previous
//
#include <hip/hip_runtime.h>

#define ALPHA 0.9f
#define THRESH 1.0f
#define BATCH 512
#define CIN 16
#define TSTEPS 2000
#define NRES 1024
#define NCLS 10

typedef float v2f __attribute__((ext_vector_type(2)));

// ws layout: [0..3]: uint max|W_res| bits (zeroed via hipMemsetAsync), Wq at +1024 (1 MB).
#define WQ_OFF 1024

// ---------------------------------------------------------------------------
// Prep 1: global max|W_res| via wave-reduce + one atomic per wave.
// ---------------------------------------------------------------------------
__global__ __launch_bounds__(256) void maxabs_kernel(const float* __restrict__ W,
                                                     unsigned* __restrict__ slot) {
    unsigned m = 0u;
    for (int i = blockIdx.x * 256 + threadIdx.x; i < NRES * NRES; i += gridDim.x * 256)
        m = max(m, __float_as_uint(W[i]) & 0x7fffffffu);
#pragma unroll
    for (int off = 32; off >= 1; off >>= 1)
        m = max(m, (unsigned)__shfl_xor((int)m, off, 64));
    if ((threadIdx.x & 63) == 0) atomicMax(slot, m);
}

// ---------------------------------------------------------------------------
// Prep 2: quantize + transpose W_res -> Wq. Row j holds 1024 offset-uint8
// (q+128, q = clamp(rint(W[n][j]*127/mx), -127, 127)) in a PERMUTED layout:
// dword g of row j = neurons {2g, 2g+1, 512+2g, 513+2g} (bytes 0..3).
// byte_pos(n) = 4*((n&511)>>1) + (n&1) + 2*(n>>9).
// ---------------------------------------------------------------------------
__global__ __launch_bounds__(256) void quantize_kernel(const float* __restrict__ W,
                                                       const unsigned* __restrict__ slot,
                                                       unsigned char* __restrict__ Wq) {
    const float mx = __uint_as_float(*slot);
    const float inv = 127.0f / mx;
    const int n = blockIdx.x;
    const int bp = 4 * ((n & 511) >> 1) + (n & 1) + 2 * (n >> 9);
#pragma unroll
    for (int k = 0; k < 4; ++k) {
        const int j = (int)threadIdx.x + 256 * k;
        float q = rintf(W[n * NRES + j] * inv);
        q = fminf(fmaxf(q, -127.f), 127.f);
        Wq[j * 1024 + bp] = (unsigned char)(int)(q + 128.f);
    }
}

// ---------------------------------------------------------------------------
// Main: one block (512 thr, 8 waves) per batch row, all TSTEPS local.
// Thread t owns neurons 2t, 2t+1 (v, count). Spikes -> ballots -> 32-word
// LDS mask; wave 0 compacts into TWO byte-offset lists (even/odd entries);
// groups (t<256 / t>=256) gather rows in parallel with exact packed-u16
// int accumulation; one LDS float2 exchange re-aligns neuron ownership.
// ---------------------------------------------------------------------------
__global__ __launch_bounds__(512, 4) void reservoir_kernel(
    const float* __restrict__ x,          // (B, C, T)
    const float* __restrict__ W_in,       // (NRES, CIN)
    const float* __restrict__ W_clf,      // (NCLS, NRES)
    const unsigned char* __restrict__ Wq, // int8 rows, 1024 B, permuted
    const unsigned* __restrict__ slot,    // max|W| bits
    float* __restrict__ out)              // [B*NCLS] ++ [B*NRES]
{
    const int b = blockIdx.x;
    const int tid = (int)threadIdx.x;
    const int lane = tid & 63;
    const int wv = tid >> 6;              // 0..7
    const int gl = tid & 255;             // lane within gather group
    const int gid = tid >> 8;             // gather group 0/1

    __shared__ float xs[2][CIN];
    __shared__ unsigned mw[2][32];
    __shared__ __align__(16) int listA[512], listB[512];
    __shared__ int cntS;
    __shared__ float2 xch[512];
    __shared__ float red[2][8][NCLS];
    __shared__ float vcS[NCLS], accS[NCLS];

    const float dscale = __uint_as_float(*slot) * (1.0f / 127.0f);

    if (tid < 32) mw[0][tid] = 0u;
    if (tid < 2 * 8 * NCLS) ((float*)red)[tid] = 0.f;
    if (tid < NCLS) { vcS[tid] = 0.f; accS[tid] = 0.f; }
    const float* xrow = x + (long)b * CIN * TSTEPS;
    if (tid < CIN) xs[0][tid] = xrow[tid * TSTEPS];

    const int n0 = 2 * tid;
    v2f win[CIN];
#pragma unroll
    for (int c = 0; c < CIN; ++c) {
        win[c].x = W_in[n0 * CIN + c];
        win[c].y = W_in[(n0 + 1) * CIN + c];
    }
    v2f wc[NCLS];
#pragma unroll
    for (int k = 0; k < NCLS; ++k) {
        wc[k].x = W_clf[k * NRES + n0];
        wc[k].y = W_clf[k * NRES + n0 + 1];
    }

    v2f vv  = {0.f, 0.f};
    v2f acc = {0.f, 0.f};

    __syncthreads();

    for (int t = 0; t < TSTEPS; ++t) {
        const int cur = t & 1;
        const int nxt = cur ^ 1;

        // ================= P1: wave-specialized prep =================
        if (wv == 0) {
            if (lane < 32) {
                unsigned m = mw[cur][lane];
                int pc = __popc(m);
#pragma unroll
                for (int off = 1; off < 32; off <<= 1) {
                    int y = __shfl_up(pc, off, 64);
                    if (lane >= off) pc += y;
                }
                int base = pc - __popc(m);
                const int jb = 128 * (lane >> 2) + ((lane & 1) << 6) + ((lane >> 1) & 1);
                while (m) {
                    int bit = __ffs((int)m) - 1;
                    m &= m - 1u;
                    const int val = (jb + 2 * bit) << 10;  // byte offset (1024 B rows)
                    if (base & 1) listB[base >> 1] = val;
                    else          listA[base >> 1] = val;
                    ++base;
                }
                if (lane == 31) cntS = pc;
            }
        } else if (wv == 1) {
            if (lane < NCLS) {
                const float sum =
                    ((red[nxt][0][lane] + red[nxt][1][lane]) + (red[nxt][2][lane] + red[nxt][3][lane])) +
                    ((red[nxt][4][lane] + red[nxt][5][lane]) + (red[nxt][6][lane] + red[nxt][7][lane]));
                float vck = ALPHA * vcS[lane] + sum;
                const float sck = (vck >= THRESH) ? 1.f : 0.f;
                accS[lane] += sck;
                vcS[lane] = (sck != 0.f) ? 0.f : vck;
            }
        } else if (wv == 2) {
            if (lane < CIN && t + 1 < TSTEPS)
                xs[nxt][lane] = xrow[lane * TSTEPS + (t + 1)];
        }

        // ---- input projection: vv = alpha*vv + x_t . W_in^T
        v2f inj = {0.f, 0.f};
        {
            const float* xc = xs[cur];
#pragma unroll
            for (int c = 0; c < CIN; ++c) {
                const float xv = xc[c];
                inj.x += xv * win[c].x;
                inj.y += xv * win[c].y;
            }
        }
        vv = ALPHA * vv + inj;

        __syncthreads();   // B1: lists + cnt ready

        // ================= P2: parallel sparse gather (exact int8) =========
        const int cnt = cntS;
        const int gcnt = gid ? (cnt >> 1) : ((cnt + 1) >> 1);
        const int* mylist = gid ? listB : listA;
        const int vo = gl << 2;
        float4 fs = {0.f, 0.f, 0.f, 0.f};
        for (int c0 = 0; c0 < gcnt; c0 += 248) {  // 248*255 < 65535: u16-safe
            const int e = min(gcnt, c0 + 248);
            unsigned a02a = 0u, a13a = 0u, a02b = 0u, a13b = 0u;
            int i = c0;
            for (; i + 8 <= e; i += 8) {
                const int4 oA = *(const int4*)&mylist[i];
                const int4 oB = *(const int4*)&mylist[i + 4];
                const unsigned u0 = *(const unsigned*)(Wq + oA.x + vo);
                const unsigned u1 = *(const unsigned*)(Wq + oA.y + vo);
                const unsigned u2 = *(const unsigned*)(Wq + oA.z + vo);
                const unsigned u3 = *(const unsigned*)(Wq + oA.w + vo);
                const unsigned u4 = *(const unsigned*)(Wq + oB.x + vo);
                const unsigned u5 = *(const unsigned*)(Wq + oB.y + vo);
                const unsigned u6 = *(const unsigned*)(Wq + oB.z + vo);
                const unsigned u7 = *(const unsigned*)(Wq + oB.w + vo);
                a02a += u0 & 0x00ff00ffu; a13a += (u0 >> 8) & 0x00ff00ffu;
                a02b += u1 & 0x00ff00ffu; a13b += (u1 >> 8) & 0x00ff00ffu;
                a02a += u2 & 0x00ff00ffu; a13a += (u2 >> 8) & 0x00ff00ffu;
                a02b += u3 & 0x00ff00ffu; a13b += (u3 >> 8) & 0x00ff00ffu;
                a02a += u4 & 0x00ff00ffu; a13a += (u4 >> 8) & 0x00ff00ffu;
                a02b += u5 & 0x00ff00ffu; a13b += (u5 >> 8) & 0x00ff00ffu;
                a02a += u6 & 0x00ff00ffu; a13a += (u6 >> 8) & 0x00ff00ffu;
                a02b += u7 & 0x00ff00ffu; a13b += (u7 >> 8) & 0x00ff00ffu;
            }
            for (; i < e; ++i) {
                const unsigned u = *(const unsigned*)(Wq + mylist[i] + vo);
                a02a += u & 0x00ff00ffu; a13a += (u >> 8) & 0x00ff00ffu;
            }
            const unsigned a02 = a02a + a02b, a13 = a13a + a13b;  // <= 63240 per lane: safe
            fs.x += (float)(a02 & 0xffffu);   // neuron 2gl
            fs.y += (float)(a13 & 0xffffu);   // neuron 2gl+1
            fs.z += (float)(a02 >> 16);       // neuron 512+2gl
            fs.w += (float)(a13 >> 16);       // neuron 513+2gl
        }

        // ---- ownership exchange: thread t owns neurons 2t,2t+1
        v2f ownp;
        if (gid == 0) { ownp.x = fs.x; ownp.y = fs.y; xch[256 + gl] = make_float2(fs.z, fs.w); }
        else          { ownp.x = fs.z; ownp.y = fs.w; xch[gl]       = make_float2(fs.x, fs.y); }
        __syncthreads();   // Bx: exchange visible
        const float2 oth = xch[tid];
        const float corr = 128.0f * (float)cnt;
        vv.x += dscale * ((ownp.x + oth.x) - corr);
        vv.y += dscale * ((ownp.y + oth.y) - corr);

        // ---- threshold / reset / count
        const float sx = (vv.x >= THRESH) ? 1.f : 0.f;
        const float sy = (vv.y >= THRESH) ? 1.f : 0.f;
        if (sx != 0.f) vv.x = 0.f;
        if (sy != 0.f) vv.y = 0.f;
        acc.x += sx; acc.y += sy;

        // ---- publish spikes via ballot
        const unsigned long long bx = __ballot(sx != 0.f);
        const unsigned long long by = __ballot(sy != 0.f);
        if (lane == 0) {
            mw[nxt][4 * wv + 0] = (unsigned)bx;
            mw[nxt][4 * wv + 1] = (unsigned)(bx >> 32);
            mw[nxt][4 * wv + 2] = (unsigned)by;
            mw[nxt][4 * wv + 3] = (unsigned)(by >> 32);
        }

        // ---- classifier partials
        float p[NCLS];
#pragma unroll
        for (int k = 0; k < NCLS; ++k)
            p[k] = sx * wc[k].x + sy * wc[k].y;
#pragma unroll
        for (int off = 32; off >= 1; off >>= 1) {
#pragma unroll
            for (int k = 0; k < NCLS; ++k) p[k] += __shfl_xor(p[k], off, 64);
        }
        if (lane == 0) {
#pragma unroll
            for (int k = 0; k < NCLS; ++k) red[cur][wv][k] = p[k];
        }

        __syncthreads();   // B2: mw[nxt] + red[cur] ready; xch/list safe to reuse
    }

    // ---- epilogue: final classifier step (last t has cur==1) + outputs
    if (wv == 1 && lane < NCLS) {
        const int k = lane;
        const float sum =
            ((red[1][0][k] + red[1][1][k]) + (red[1][2][k] + red[1][3][k])) +
            ((red[1][4][k] + red[1][5][k]) + (red[1][6][k] + red[1][7][k]));
        const float vck = ALPHA * vcS[k] + sum;
        const float sck = (vck >= THRESH) ? 1.f : 0.f;
        out[b * NCLS + k] = accS[k] + sck;
    }
    float2* outr = (float2*)(out + BATCH * NCLS + (long)b * NRES);
    outr[tid] = make_float2(acc.x, acc.y);
}

extern "C" void kernel_launch(void* const* d_in, const int* in_sizes, int n_in,
                              void* d_out, int out_size, void* d_ws, size_t ws_size,
                              hipStream_t stream) {
    (void)in_sizes; (void)n_in; (void)out_size; (void)ws_size;
    const float* x     = (const float*)d_in[0];
    const float* W_in  = (const float*)d_in[1];
    const float* W_res = (const float*)d_in[2];
    const float* W_clf = (const float*)d_in[3];
    float* out = (float*)d_out;
    unsigned* slot = (unsigned*)d_ws;
    unsigned char* Wq = (unsigned char*)d_ws + WQ_OFF;

    hipMemsetAsync(slot, 0, 4, stream);
    maxabs_kernel<<<256, 256, 0, stream>>>(W_res, slot);
    quantize_kernel<<<NRES, 256, 0, stream>>>(W_res, slot, Wq);
    reservoir_kernel<<<BATCH, 512, 0, stream>>>(x, W_in, W_clf, Wq, slot, out);
}